// Round 14
// baseline (205.046 us; speedup 1.0000x reference)
//
#include <hip/hip_runtime.h>
#include <cstddef>

#define B_ 2
#define NQ_ 10000
#define C_ 256
#define M_ 8
#define L_ 3
#define K_ 4
#define D_ 32
#define P_ 13125   // 10000 + 2500 + 625

typedef unsigned short u16;
typedef __attribute__((ext_vector_type(8))) short short8;
typedef __attribute__((ext_vector_type(4))) float f32x4;

static __device__ __forceinline__ u16 f2bf(float f) {
    union { float f; unsigned u; } x; x.f = f;
    unsigned r = x.u + 0x7fffu + ((x.u >> 16) & 1u);   // RNE
    return (u16)(r >> 16);
}
static __device__ __forceinline__ short8 cvt8(const float4& a, const float4& b) {
    short8 r;
    r[0] = (short)f2bf(a.x); r[1] = (short)f2bf(a.y);
    r[2] = (short)f2bf(a.z); r[3] = (short)f2bf(a.w);
    r[4] = (short)f2bf(b.x); r[5] = (short)f2bf(b.y);
    r[6] = (short)f2bf(b.z); r[7] = (short)f2bf(b.w);
    return r;
}

// ---------------------------------------------------------------------------
// cvt_wq: weights f32->bf16 (bid<100) + query f32->bf16 (bid 100..2599).
// ---------------------------------------------------------------------------
__global__ __launch_bounds__(256) void cvt_wq(
    const float* __restrict__ Wv, const float* __restrict__ Ws,
    const float* __restrict__ Wa, const float* __restrict__ Wo,
    u16* __restrict__ wb,
    const float* __restrict__ query, u16* __restrict__ qbf)
{
    const int bid = blockIdx.x;
    const int t   = threadIdx.x;
    if (bid < 100) {
        const int i = bid * 256 + t;
        if (i >= 25600) return;
        const int g = i * 8;
        const float* src;
        if (g < 65536)       src = Wv + g;
        else if (g < 114688) src = Ws + (g - 65536);
        else if (g < 139264) src = Wa + (g - 114688);
        else                 src = Wo + (g - 139264);
        const float4 a = *reinterpret_cast<const float4*>(src);
        const float4 b = *reinterpret_cast<const float4*>(src + 4);
        *reinterpret_cast<short8*>(wb + g) = cvt8(a, b);
    } else {
        const int i = (bid - 100) * 256 + t;
        const float4 a = *reinterpret_cast<const float4*>(query + (size_t)i * 8);
        const float4 b = *reinterpret_cast<const float4*>(query + (size_t)i * 8 + 4);
        *reinterpret_cast<short8*>(qbf + (size_t)i * 8) = cvt8(a, b);
    }
}

// ---------------------------------------------------------------------------
// trans_s: S-GEMM (bid<400, latency-bound, HBM idle) CO-RESIDENT with the
// value transpose (bid 400..2283, HBM-bound) — the transpose soaks idle
// bandwidth under the S-GEMM's stalls. Both 512-thr. Bodies identical to
// the R13-proven code.
//   S:  S = qbf[20000,256] @ [Ws;Wa]^T + [bs;ba] -> f32, 79 tiles x 5 panels
//   T:  v [b][c][p] f32 -> Vt [b][pixel][c] bf16; 2 64x64 tiles per block.
// ---------------------------------------------------------------------------
__global__ __launch_bounds__(512) void trans_s(
    const float* __restrict__ v0, const float* __restrict__ v1,
    const float* __restrict__ v2, u16* __restrict__ Vt,
    const u16* __restrict__ qbf,
    const u16* __restrict__ Wsb, const float* __restrict__ bs,
    const u16* __restrict__ Wab, const float* __restrict__ ba,
    float* __restrict__ S)
{
    __shared__ u16 Bs[64 * 264];
    const int t = threadIdx.x;

    if (blockIdx.x < 400) {
        // ------------------- S-GEMM (jobS path, verbatim) -------------------
        const int bid = blockIdx.x;
        const int rlo  = bid & 7;
        const int tmp  = bid >> 3;
        const int panel = tmp % 5;
        const int rowTile = (tmp / 5) * 8 + rlo;
        if (rowTile >= 79) return;

        const int rows = B_ * NQ_;
        const int N1 = 192, Ntot = 288;

        const int w  = t >> 6;
        const int l  = t & 63;
        const int row0 = rowTile * 256 + w * 32;
        const int o0   = panel * 64;
        const int lr = l & 15;
        const int kb = (l >> 4) * 8;

        const int ra0 = min(row0 + lr,      rows - 1);
        const int ra1 = min(row0 + 16 + lr, rows - 1);
        const u16* Ap0 = qbf + (size_t)ra0 * 256 + kb;
        const u16* Ap1 = qbf + (size_t)ra1 * 256 + kb;

        short8 A0[4], A1[4];
        #pragma unroll
        for (int i = 0; i < 4; ++i) {
            A0[i] = *reinterpret_cast<const short8*>(Ap0 + i * 32);
            A1[i] = *reinterpret_cast<const short8*>(Ap1 + i * 32);
        }

        #pragma unroll
        for (int i = 0; i < 4; ++i) {
            int idx = i * 512 + t;
            int col = idx >> 5;
            int kc  = (idx & 31) * 8;
            int colg = min(o0 + col, Ntot - 1);
            const u16* Br = ((colg < N1) ? Wsb + (size_t)colg * 256
                                         : Wab + (size_t)(colg - N1) * 256) + kc;
            *reinterpret_cast<short8*>(&Bs[col * 264 + kc]) =
                *reinterpret_cast<const short8*>(Br);
        }

        __syncthreads();

        short8 A0b[4], A1b[4];
        #pragma unroll
        for (int i = 0; i < 4; ++i) {
            A0b[i] = *reinterpret_cast<const short8*>(Ap0 + 128 + i * 32);
            A1b[i] = *reinterpret_cast<const short8*>(Ap1 + 128 + i * 32);
        }

        f32x4 acc[2][4] = {};
        #pragma unroll
        for (int i = 0; i < 8; ++i) {
            const int k0 = i * 32;
            short8 a0 = (i < 4) ? A0[i] : A0b[i - 4];
            short8 a1 = (i < 4) ? A1[i] : A1b[i - 4];
            short8 b0 = *reinterpret_cast<const short8*>(&Bs[(0 * 16 + lr) * 264 + kb + k0]);
            short8 b1 = *reinterpret_cast<const short8*>(&Bs[(1 * 16 + lr) * 264 + kb + k0]);
            short8 b2 = *reinterpret_cast<const short8*>(&Bs[(2 * 16 + lr) * 264 + kb + k0]);
            short8 b3 = *reinterpret_cast<const short8*>(&Bs[(3 * 16 + lr) * 264 + kb + k0]);
            acc[0][0] = __builtin_amdgcn_mfma_f32_16x16x32_bf16(a0, b0, acc[0][0], 0, 0, 0);
            acc[0][1] = __builtin_amdgcn_mfma_f32_16x16x32_bf16(a0, b1, acc[0][1], 0, 0, 0);
            acc[0][2] = __builtin_amdgcn_mfma_f32_16x16x32_bf16(a0, b2, acc[0][2], 0, 0, 0);
            acc[0][3] = __builtin_amdgcn_mfma_f32_16x16x32_bf16(a0, b3, acc[0][3], 0, 0, 0);
            acc[1][0] = __builtin_amdgcn_mfma_f32_16x16x32_bf16(a1, b0, acc[1][0], 0, 0, 0);
            acc[1][1] = __builtin_amdgcn_mfma_f32_16x16x32_bf16(a1, b1, acc[1][1], 0, 0, 0);
            acc[1][2] = __builtin_amdgcn_mfma_f32_16x16x32_bf16(a1, b2, acc[1][2], 0, 0, 0);
            acc[1][3] = __builtin_amdgcn_mfma_f32_16x16x32_bf16(a1, b3, acc[1][3], 0, 0, 0);
        }

        const int orow = (l >> 4) * 4;
        #pragma unroll
        for (int ct = 0; ct < 4; ++ct) {
            const int col = o0 + ct * 16 + lr;
            if (col >= Ntot) continue;
            const float bsv = (col < N1) ? bs[col] : ba[col - N1];
            #pragma unroll
            for (int rt = 0; rt < 2; ++rt) {
                #pragma unroll
                for (int r = 0; r < 4; ++r) {
                    const int row = row0 + rt * 16 + orow + r;
                    if (row < rows)
                        S[(size_t)row * 288 + col] = acc[rt][ct][r] + bsv;
                }
            }
        }
    } else {
        // ------------- transpose: 2x 64x64 tiles per 512-thr block ---------
        constexpr int HWs[3]  = {10000, 2500, 625};
        constexpr int offs[3] = {0, 10000, 12500};
        const int tb = blockIdx.x - 400;           // 0..1883 = 157*2*6
        const int x = tb % 157;
        const int y = (tb / 157) % 2;
        const int z = tb / 314;
        const int b   = z / 3;
        const int lvl = z % 3;
        const int HW  = HWs[lvl];
        const int p0  = x * 64;
        if (p0 >= HW) return;

        u16 (*tile)[64][66] = reinterpret_cast<u16 (*)[64][66]>(Bs);  // 2x8.4KB
        const int cc = t >> 8;            // half 0/1
        const int tt = t & 255;
        const int c0 = y * 128 + cc * 64;

        const float* V = (lvl == 0 ? v0 : (lvl == 1 ? v1 : v2)) + (size_t)b * 256 * HW;

        const int pl = tt & 63;
        const int cb = tt >> 6;   // 0..3
        #pragma unroll
        for (int i = 0; i < 16; ++i) {
            int c = cb + i * 4;
            float vv = 0.f;
            if (p0 + pl < HW)
                vv = V[(size_t)(c0 + c) * HW + p0 + pl];
            tile[cc][pl][c] = f2bf(vv);
        }
        __syncthreads();

        const int cl = tt & 63;
        const int pb = tt >> 6;
        #pragma unroll
        for (int i = 0; i < 16; ++i) {
            int p = pb + i * 4;
            if (p0 + p < HW)
                Vt[((size_t)b * P_ + offs[lvl] + p0 + p) * 256 + c0 + cl] = tile[cc][p][cl];
        }
    }
}

// ---------------------------------------------------------------------------
// proj-GEMM (R13 proj path verbatim): proj = Vt @ Wv^T + bv -> u16,
// 103 tiles x 4 panels = 416 blocks, LDS-staged coalesced epilogue.
// ---------------------------------------------------------------------------
__global__ __launch_bounds__(512) void gemm_proj(
    const u16* __restrict__ Vt,
    const u16* __restrict__ Wvb, const float* __restrict__ bv,
    u16* __restrict__ proj)
{
    __shared__ u16 Bs[64 * 264];

    const int bid = blockIdx.x;
    const int rlo  = bid & 7;
    const int tmp  = bid >> 3;
    const int panel = tmp % 4;
    const int rowTile = (tmp / 4) * 8 + rlo;
    if (rowTile >= 103) return;

    const int rows = B_ * P_;

    const int t  = threadIdx.x;
    const int w  = t >> 6;
    const int l  = t & 63;
    const int row0 = rowTile * 256 + w * 32;
    const int o0   = panel * 64;
    const int lr = l & 15;
    const int kb = (l >> 4) * 8;

    const int ra0 = min(row0 + lr,      rows - 1);
    const int ra1 = min(row0 + 16 + lr, rows - 1);
    const u16* Ap0 = Vt + (size_t)ra0 * 256 + kb;
    const u16* Ap1 = Vt + (size_t)ra1 * 256 + kb;

    short8 A0[4], A1[4];
    #pragma unroll
    for (int i = 0; i < 4; ++i) {
        A0[i] = *reinterpret_cast<const short8*>(Ap0 + i * 32);
        A1[i] = *reinterpret_cast<const short8*>(Ap1 + i * 32);
    }

    #pragma unroll
    for (int i = 0; i < 4; ++i) {
        int idx = i * 512 + t;
        int col = idx >> 5;
        int kc  = (idx & 31) * 8;
        *reinterpret_cast<short8*>(&Bs[col * 264 + kc]) =
            *reinterpret_cast<const short8*>(Wvb + (size_t)(o0 + col) * 256 + kc);
    }

    __syncthreads();

    short8 A0b[4], A1b[4];
    #pragma unroll
    for (int i = 0; i < 4; ++i) {
        A0b[i] = *reinterpret_cast<const short8*>(Ap0 + 128 + i * 32);
        A1b[i] = *reinterpret_cast<const short8*>(Ap1 + 128 + i * 32);
    }

    f32x4 acc[2][4] = {};
    #pragma unroll
    for (int i = 0; i < 8; ++i) {
        const int k0 = i * 32;
        short8 a0 = (i < 4) ? A0[i] : A0b[i - 4];
        short8 a1 = (i < 4) ? A1[i] : A1b[i - 4];
        short8 b0 = *reinterpret_cast<const short8*>(&Bs[(0 * 16 + lr) * 264 + kb + k0]);
        short8 b1 = *reinterpret_cast<const short8*>(&Bs[(1 * 16 + lr) * 264 + kb + k0]);
        short8 b2 = *reinterpret_cast<const short8*>(&Bs[(2 * 16 + lr) * 264 + kb + k0]);
        short8 b3 = *reinterpret_cast<const short8*>(&Bs[(3 * 16 + lr) * 264 + kb + k0]);
        acc[0][0] = __builtin_amdgcn_mfma_f32_16x16x32_bf16(a0, b0, acc[0][0], 0, 0, 0);
        acc[0][1] = __builtin_amdgcn_mfma_f32_16x16x32_bf16(a0, b1, acc[0][1], 0, 0, 0);
        acc[0][2] = __builtin_amdgcn_mfma_f32_16x16x32_bf16(a0, b2, acc[0][2], 0, 0, 0);
        acc[0][3] = __builtin_amdgcn_mfma_f32_16x16x32_bf16(a0, b3, acc[0][3], 0, 0, 0);
        acc[1][0] = __builtin_amdgcn_mfma_f32_16x16x32_bf16(a1, b0, acc[1][0], 0, 0, 0);
        acc[1][1] = __builtin_amdgcn_mfma_f32_16x16x32_bf16(a1, b1, acc[1][1], 0, 0, 0);
        acc[1][2] = __builtin_amdgcn_mfma_f32_16x16x32_bf16(a1, b2, acc[1][2], 0, 0, 0);
        acc[1][3] = __builtin_amdgcn_mfma_f32_16x16x32_bf16(a1, b3, acc[1][3], 0, 0, 0);
    }

    const int orow = (l >> 4) * 4;
    // LDS-staged u16 epilogue (Bs dead after k-loop)
    __syncthreads();
    #pragma unroll
    for (int ct = 0; ct < 4; ++ct) {
        const int col = ct * 16 + lr;          // 0..63 within panel
        const float bsv = bv[o0 + col];
        #pragma unroll
        for (int rt = 0; rt < 2; ++rt) {
            #pragma unroll
            for (int r = 0; r < 4; ++r) {
                const int rowL = w * 32 + rt * 16 + orow + r;   // 0..255
                Bs[rowL * 64 + col] = f2bf(acc[rt][ct][r] + bsv);
            }
        }
    }
    __syncthreads();
    const int rowL = t >> 1;
    const int half = (t & 1) * 32;
    const int grow = rowTile * 256 + rowL;
    if (grow < rows) {
        const short8* src = reinterpret_cast<const short8*>(&Bs[rowL * 64 + half]);
        short8* dst = reinterpret_cast<short8*>(proj + (size_t)grow * 256 + o0 + half);
        dst[0] = src[0]; dst[1] = src[1];
        dst[2] = src[2]; dst[3] = src[3];
    }
}

// ---------------------------------------------------------------------------
// Output projection GEMM (R10 hoisted-A, unchanged — f32 out, 64B segments).
// ---------------------------------------------------------------------------
__global__ __launch_bounds__(512) void gemm_out(
    const u16* __restrict__ Av, int rows, int nRowTiles, int npanel,
    const u16* __restrict__ Bb, const float* __restrict__ bias, int Ntot,
    float* __restrict__ Cout)
{
    __shared__ u16 Bs[64 * 264];

    const int bid  = blockIdx.x;
    const int rlo  = bid & 7;
    const int tmp  = bid >> 3;
    const int panel = tmp % npanel;
    const int rowTile = (tmp / npanel) * 8 + rlo;
    if (rowTile >= nRowTiles) return;

    const int t  = threadIdx.x;
    const int w  = t >> 6;
    const int l  = t & 63;
    const int row0 = rowTile * 256 + w * 32;
    const int o0   = panel * 64;
    const int lr = l & 15;
    const int kb = (l >> 4) * 8;

    const int ra0 = min(row0 + lr,      rows - 1);
    const int ra1 = min(row0 + 16 + lr, rows - 1);
    const u16* Ap0 = Av + (size_t)ra0 * 256 + kb;
    const u16* Ap1 = Av + (size_t)ra1 * 256 + kb;

    short8 A0[4], A1[4];
    #pragma unroll
    for (int i = 0; i < 4; ++i) {
        A0[i] = *reinterpret_cast<const short8*>(Ap0 + i * 32);
        A1[i] = *reinterpret_cast<const short8*>(Ap1 + i * 32);
    }

    #pragma unroll
    for (int i = 0; i < 4; ++i) {
        int idx = i * 512 + t;
        int col = idx >> 5;
        int kc  = (idx & 31) * 8;
        int colg = min(o0 + col, Ntot - 1);
        *reinterpret_cast<short8*>(&Bs[col * 264 + kc]) =
            *reinterpret_cast<const short8*>(Bb + (size_t)colg * 256 + kc);
    }

    __syncthreads();

    short8 A0b[4], A1b[4];
    #pragma unroll
    for (int i = 0; i < 4; ++i) {
        A0b[i] = *reinterpret_cast<const short8*>(Ap0 + 128 + i * 32);
        A1b[i] = *reinterpret_cast<const short8*>(Ap1 + 128 + i * 32);
    }

    f32x4 acc[2][4] = {};
    #pragma unroll
    for (int i = 0; i < 8; ++i) {
        const int k0 = i * 32;
        short8 a0 = (i < 4) ? A0[i] : A0b[i - 4];
        short8 a1 = (i < 4) ? A1[i] : A1b[i - 4];
        short8 b0 = *reinterpret_cast<const short8*>(&Bs[(0 * 16 + lr) * 264 + kb + k0]);
        short8 b1 = *reinterpret_cast<const short8*>(&Bs[(1 * 16 + lr) * 264 + kb + k0]);
        short8 b2 = *reinterpret_cast<const short8*>(&Bs[(2 * 16 + lr) * 264 + kb + k0]);
        short8 b3 = *reinterpret_cast<const short8*>(&Bs[(3 * 16 + lr) * 264 + kb + k0]);
        acc[0][0] = __builtin_amdgcn_mfma_f32_16x16x32_bf16(a0, b0, acc[0][0], 0, 0, 0);
        acc[0][1] = __builtin_amdgcn_mfma_f32_16x16x32_bf16(a0, b1, acc[0][1], 0, 0, 0);
        acc[0][2] = __builtin_amdgcn_mfma_f32_16x16x32_bf16(a0, b2, acc[0][2], 0, 0, 0);
        acc[0][3] = __builtin_amdgcn_mfma_f32_16x16x32_bf16(a0, b3, acc[0][3], 0, 0, 0);
        acc[1][0] = __builtin_amdgcn_mfma_f32_16x16x32_bf16(a1, b0, acc[1][0], 0, 0, 0);
        acc[1][1] = __builtin_amdgcn_mfma_f32_16x16x32_bf16(a1, b1, acc[1][1], 0, 0, 0);
        acc[1][2] = __builtin_amdgcn_mfma_f32_16x16x32_bf16(a1, b2, acc[1][2], 0, 0, 0);
        acc[1][3] = __builtin_amdgcn_mfma_f32_16x16x32_bf16(a1, b3, acc[1][3], 0, 0, 0);
    }

    const int orow = (l >> 4) * 4;
    #pragma unroll
    for (int ct = 0; ct < 4; ++ct) {
        const int col = o0 + ct * 16 + lr;
        if (col >= Ntot) continue;
        const float bsv = bias[col];
        #pragma unroll
        for (int rt = 0; rt < 2; ++rt) {
            #pragma unroll
            for (int r = 0; r < 4; ++r) {
                const int row = row0 + rt * 16 + orow + r;
                if (row < rows)
                    Cout[(size_t)row * Ntot + col] = acc[rt][ct][r] + bsv;
            }
        }
    }
}

// ---------------------------------------------------------------------------
// Sampling (R1-proven, 5x confirmed at 41.3us): 2 queries/block,
// 2 channels/thread. Gather-latency/L3-bound -> maximize concurrent gather
// threads; deeper per-thread work regresses (R2, R11).
// ---------------------------------------------------------------------------
__global__ __launch_bounds__(256) void sample_kernel(
    const float* __restrict__ S,       // [B*NQ, 288]
    const float* __restrict__ refp,    // [B*NQ, 2]
    const u16* __restrict__ proj,      // [B, P_, 256] bf16
    u16* __restrict__ out2)            // [B*NQ, 256] bf16
{
    constexpr int Wd[3]   = {100, 50, 25};
    constexpr int offs[3] = {0, 10000, 12500};

    __shared__ int   midx[192][4];
    __shared__ float mw[192][4];

    const int t = threadIdx.x;

    if (t < 192) {
        const int q  = t / 96;
        const int tq = t % 96;
        const int tm = tq / 12;      // head
        const int tj = tq % 12;      // point = l*4+k
        const int bq = blockIdx.x * 2 + q;
        const float* Sq = S + (size_t)bq * 288;

        float lg[12], mx = -1e30f;
        #pragma unroll
        for (int jj = 0; jj < 12; ++jj) {
            lg[jj] = Sq[192 + tm * 12 + jj];
            mx = fmaxf(mx, lg[jj]);
        }
        float sum = 0.f;
        #pragma unroll
        for (int jj = 0; jj < 12; ++jj) sum += __expf(lg[jj] - mx);
        const float attn = __expf(lg[tj] - mx) / sum;

        const int l  = tj >> 2;
        const int Wl = Wd[l];
        const float refx = refp[(size_t)bq * 2 + 0];
        const float refy = refp[(size_t)bq * 2 + 1];
        const float ox = Sq[(tm * 12 + tj) * 2 + 0];
        const float oy = Sq[(tm * 12 + tj) * 2 + 1];
        const float px = refx * (float)Wl + ox - 0.5f;   // H==W per level
        const float py = refy * (float)Wl + oy - 0.5f;
        const float x0f = floorf(px), y0f = floorf(py);
        const float wx1 = px - x0f, wy1 = py - y0f;
        const float wx0 = 1.f - wx1, wy0 = 1.f - wy1;
        const int x0 = (int)x0f, y0 = (int)y0f;
        const int x1 = x0 + 1, y1 = y0 + 1;
        const bool vx0 = (unsigned)x0 < (unsigned)Wl;
        const bool vx1 = (unsigned)x1 < (unsigned)Wl;
        const bool vy0 = (unsigned)y0 < (unsigned)Wl;
        const bool vy1 = (unsigned)y1 < (unsigned)Wl;
        const int chb  = tm * 32;
        const int base = offs[l];
        midx[t][0] = (vx0 && vy0) ? ((base + y0 * Wl + x0) * 256 + chb) : 0;
        midx[t][1] = (vx1 && vy0) ? ((base + y0 * Wl + x1) * 256 + chb) : 0;
        midx[t][2] = (vx0 && vy1) ? ((base + y1 * Wl + x0) * 256 + chb) : 0;
        midx[t][3] = (vx1 && vy1) ? ((base + y1 * Wl + x1) * 256 + chb) : 0;
        mw[t][0] = (vx0 && vy0) ? attn * wx0 * wy0 : 0.f;
        mw[t][1] = (vx1 && vy0) ? attn * wx1 * wy0 : 0.f;
        mw[t][2] = (vx0 && vy1) ? attn * wx0 * wy1 : 0.f;
        mw[t][3] = (vx1 && vy1) ? attn * wx1 * wy1 : 0.f;
    }
    __syncthreads();

    const int qi  = t >> 7;
    const int tt  = t & 127;
    const int mh  = tt >> 4;
    const int d16 = tt & 15;
    const int bq2 = blockIdx.x * 2 + qi;
    const int b   = bq2 / NQ_;
    const u16* projb = proj + (size_t)b * P_ * 256 + 2 * d16;

    float acc0 = 0.f, acc1 = 0.f;

    #pragma unroll
    for (int j = 0; j < 12; ++j) {
        const int mj = qi * 96 + mh * 12 + j;
        const int4   o  = *reinterpret_cast<const int4*>(midx[mj]);
        const float4 ww = *reinterpret_cast<const float4*>(mw[mj]);
        const unsigned u00 = *reinterpret_cast<const unsigned*>(projb + o.x);
        const unsigned u10 = *reinterpret_cast<const unsigned*>(projb + o.y);
        const unsigned u01 = *reinterpret_cast<const unsigned*>(projb + o.z);
        const unsigned u11 = *reinterpret_cast<const unsigned*>(projb + o.w);
        union { unsigned u; float f; } c0, c1;
        c0.u = u00 << 16;          c1.u = u00 & 0xffff0000u;
        acc0 = fmaf(ww.x, c0.f, acc0); acc1 = fmaf(ww.x, c1.f, acc1);
        c0.u = u10 << 16;          c1.u = u10 & 0xffff0000u;
        acc0 = fmaf(ww.y, c0.f, acc0); acc1 = fmaf(ww.y, c1.f, acc1);
        c0.u = u01 << 16;          c1.u = u01 & 0xffff0000u;
        acc0 = fmaf(ww.z, c0.f, acc0); acc1 = fmaf(ww.z, c1.f, acc1);
        c0.u = u11 << 16;          c1.u = u11 & 0xffff0000u;
        acc0 = fmaf(ww.w, c0.f, acc0); acc1 = fmaf(ww.w, c1.f, acc1);
    }

    const unsigned packed = (unsigned)f2bf(acc0) | ((unsigned)f2bf(acc1) << 16);
    *reinterpret_cast<unsigned*>(out2 + (size_t)bq2 * 256 + mh * 32 + 2 * d16) = packed;
}

// ---------------------------------------------------------------------------
extern "C" void kernel_launch(void* const* d_in, const int* in_sizes, int n_in,
                              void* d_out, int out_size, void* d_ws, size_t ws_size,
                              hipStream_t stream)
{
    const float* query = (const float*)d_in[0];
    const float* refp  = (const float*)d_in[1];
    const float* v0    = (const float*)d_in[2];
    const float* v1    = (const float*)d_in[3];
    const float* v2    = (const float*)d_in[4];
    const float* Wv    = (const float*)d_in[5];
    const float* bv    = (const float*)d_in[6];
    const float* Ws    = (const float*)d_in[7];
    const float* bs    = (const float*)d_in[8];
    const float* Wa    = (const float*)d_in[9];
    const float* ba    = (const float*)d_in[10];
    const float* Wo    = (const float*)d_in[11];
    const float* bo    = (const float*)d_in[12];
    float* out = (float*)d_out;

    char* wsb = (char*)d_ws;
    u16*   proj  = (u16*)wsb;    wsb += (size_t)B_ * P_ * 256 * 2;   // 13.44 MB
    float* S     = (float*)wsb;  wsb += (size_t)B_ * NQ_ * 288 * 4;  // 23.04 MB
    u16*   Vt    = (u16*)wsb;    wsb += (size_t)B_ * P_ * 256 * 2;   // 13.44 MB
    u16*   out2  = (u16*)wsb;    wsb += (size_t)B_ * NQ_ * 256 * 2;  // 10.24 MB
    u16*   qbf   = (u16*)wsb;    wsb += (size_t)B_ * NQ_ * 256 * 2;  // 10.24 MB
    u16*   wb    = (u16*)wsb;    wsb += (size_t)204800 * 2;          // 0.4 MB
    u16* Wvb = wb;
    u16* Wsb = wb + 65536;
    u16* Wab = wb + 114688;
    u16* Wob = wb + 139264;

    // 0) weights + query cvt (2600 blocks)
    cvt_wq<<<dim3(2600), dim3(256), 0, stream>>>(Wv, Ws, Wa, Wo, wb, query, qbf);

    // 1) S-GEMM (400 blocks, latency-bound) CO-RESIDENT with transpose
    //    (1884 blocks, HBM-bound): 2284 x 512 thr.
    trans_s<<<dim3(2284), dim3(512), 0, stream>>>(
        v0, v1, v2, Vt, qbf, Wsb, bs, Wab, ba, S);

    // 2) proj GEMM (needs Vt): 416 blocks.
    gemm_proj<<<dim3(416), dim3(512), 0, stream>>>(Vt, Wvb, bv, proj);

    // 3) softmax + bilinear sampling -> out2 bf16 (2 queries / block)
    sample_kernel<<<dim3(NQ_), dim3(256), 0, stream>>>(S, refp, proj, out2);

    // 4) output projection -> d_out f32. 320 blocks.
    gemm_out<<<dim3(320), dim3(512), 0, stream>>>(
        out2, B_ * NQ_, 79, 4, Wob, bo, 256, out);
}

// Round 15
// 188.996 us; speedup vs baseline: 1.0849x; 1.0849x over previous
//
#include <hip/hip_runtime.h>
#include <cstddef>

#define B_ 2
#define NQ_ 10000
#define C_ 256
#define M_ 8
#define L_ 3
#define K_ 4
#define D_ 32
#define P_ 13125   // 10000 + 2500 + 625

typedef unsigned short u16;
typedef __attribute__((ext_vector_type(8))) short short8;
typedef __attribute__((ext_vector_type(4))) float f32x4;

static __device__ __forceinline__ u16 f2bf(float f) {
    union { float f; unsigned u; } x; x.f = f;
    unsigned r = x.u + 0x7fffu + ((x.u >> 16) & 1u);   // RNE
    return (u16)(r >> 16);
}
static __device__ __forceinline__ short8 cvt8(const float4& a, const float4& b) {
    short8 r;
    r[0] = (short)f2bf(a.x); r[1] = (short)f2bf(a.y);
    r[2] = (short)f2bf(a.z); r[3] = (short)f2bf(a.w);
    r[4] = (short)f2bf(b.x); r[5] = (short)f2bf(b.y);
    r[6] = (short)f2bf(b.z); r[7] = (short)f2bf(b.w);
    return r;
}

// ---------------------------------------------------------------------------
// PREP (merged, R13-proven): value transpose (blocks 0..3767) + weight cvt
// (3768..3867) + query cvt (3868..6367).
// ---------------------------------------------------------------------------
__global__ __launch_bounds__(256) void prep(
    const float* __restrict__ v0, const float* __restrict__ v1,
    const float* __restrict__ v2, u16* __restrict__ Vt,
    const float* __restrict__ Wv, const float* __restrict__ Ws,
    const float* __restrict__ Wa, const float* __restrict__ Wo,
    u16* __restrict__ wb,
    const float* __restrict__ query, u16* __restrict__ qbf)
{
    __shared__ u16 tile[64][66];
    const int bid = blockIdx.x;
    const int t   = threadIdx.x;

    if (bid < 3768) {
        constexpr int HWs[3]  = {10000, 2500, 625};
        constexpr int offs[3] = {0, 10000, 12500};
        const int x = bid % 157;
        const int y = (bid / 157) % 4;
        const int z = bid / 628;
        const int b   = z / 3;
        const int lvl = z % 3;
        const int HW  = HWs[lvl];
        const int p0  = x * 64;
        if (p0 >= HW) return;
        const int c0  = y * 64;

        const float* V = (lvl == 0 ? v0 : (lvl == 1 ? v1 : v2)) + (size_t)b * 256 * HW;

        const int pl = t & 63;
        const int cb = t >> 6;   // 0..3
        #pragma unroll
        for (int i = 0; i < 16; ++i) {
            int c = cb + i * 4;
            float vv = 0.f;
            if (p0 + pl < HW)
                vv = V[(size_t)(c0 + c) * HW + p0 + pl];
            tile[pl][c] = f2bf(vv);
        }
        __syncthreads();

        const int cl = t & 63;
        const int pb = t >> 6;
        #pragma unroll
        for (int i = 0; i < 16; ++i) {
            int p = pb + i * 4;
            if (p0 + p < HW)
                Vt[((size_t)b * P_ + offs[lvl] + p0 + p) * 256 + c0 + cl] = tile[p][cl];
        }
    } else if (bid < 3868) {
        const int i = (bid - 3768) * 256 + t;
        if (i >= 25600) return;
        const int g = i * 8;
        const float* src;
        if (g < 65536)       src = Wv + g;
        else if (g < 114688) src = Ws + (g - 65536);
        else if (g < 139264) src = Wa + (g - 114688);
        else                 src = Wo + (g - 139264);
        const float4 a = *reinterpret_cast<const float4*>(src);
        const float4 b = *reinterpret_cast<const float4*>(src + 4);
        *reinterpret_cast<short8*>(wb + g) = cvt8(a, b);
    } else {
        const int i = (bid - 3868) * 256 + t;
        const float4 a = *reinterpret_cast<const float4*>(query + (size_t)i * 8);
        const float4 b = *reinterpret_cast<const float4*>(query + (size_t)i * 8 + 4);
        *reinterpret_cast<short8*>(qbf + (size_t)i * 8) = cvt8(a, b);
    }
}

// ---------------------------------------------------------------------------
// FUSED proj+S GEMM (R13-proven) with HEAD-MAJOR proj output:
// proj layout [b][m][pix][32] so that in sample, x-adjacent corner rows are
// 64B apart (x0/x1 pair often shares one 128B line -> fewer line fetches).
// Copy-out: each thread's 32-u16 half-row = exactly one head's channels,
// still 64B contiguous.
//   bid <  416: proj = Vt[26250,256] @ Wv^T + bv -> u16, 103 tiles x 4 panels
//   bid >= 416: S = qbf[20000,256] @ [Ws;Wa]^T -> f32, 79 tiles x 5 panels
// ---------------------------------------------------------------------------
__global__ __launch_bounds__(512) void gemm_fused(
    const u16* __restrict__ Vt, const u16* __restrict__ qbf,
    const u16* __restrict__ Wvb, const float* __restrict__ bv,
    const u16* __restrict__ Wsb, const float* __restrict__ bs,
    const u16* __restrict__ Wab, const float* __restrict__ ba,
    u16* __restrict__ proj, float* __restrict__ S)
{
    __shared__ u16 Bs[64 * 264];

    const bool jobS = (blockIdx.x >= 416);
    const int  bid  = jobS ? (blockIdx.x - 416) : blockIdx.x;

    const int npanel    = jobS ? 5 : 4;
    const int nRowTiles = jobS ? 79 : 103;
    const int rows      = jobS ? (B_ * NQ_) : (B_ * P_);
    const int N1        = jobS ? 192 : 256;
    const int Ntot      = jobS ? 288 : 256;
    const u16* Aimg     = jobS ? qbf : Vt;
    const u16* B1b      = jobS ? Wsb : Wvb;
    const u16* B2b      = jobS ? Wab : Wvb;
    const float* bias1  = jobS ? bs : bv;
    const float* bias2  = jobS ? ba : bv;

    const int rlo  = bid & 7;
    const int tmp  = bid >> 3;
    const int panel = tmp % npanel;
    const int rowTile = (tmp / npanel) * 8 + rlo;
    if (rowTile >= nRowTiles) return;

    const int t  = threadIdx.x;
    const int w  = t >> 6;            // wave 0..7
    const int l  = t & 63;
    const int row0 = rowTile * 256 + w * 32;
    const int o0   = panel * 64;
    const int lr = l & 15;
    const int kb = (l >> 4) * 8;

    const int ra0 = min(row0 + lr,      rows - 1);
    const int ra1 = min(row0 + 16 + lr, rows - 1);
    const u16* Ap0 = Aimg + (size_t)ra0 * 256 + kb;
    const u16* Ap1 = Aimg + (size_t)ra1 * 256 + kb;

    // ---- batch 1: A fragments k=0..127, in flight before staging ----
    short8 A0[4], A1[4];
    #pragma unroll
    for (int i = 0; i < 4; ++i) {
        A0[i] = *reinterpret_cast<const short8*>(Ap0 + i * 32);
        A1[i] = *reinterpret_cast<const short8*>(Ap1 + i * 32);
    }

    // stage B panel: 64 cols x 256 k (4 iters x 512 thr x 8 el)
    #pragma unroll
    for (int i = 0; i < 4; ++i) {
        int idx = i * 512 + t;
        int col = idx >> 5;
        int kc  = (idx & 31) * 8;
        int colg = min(o0 + col, Ntot - 1);
        const u16* Br = ((colg < N1) ? B1b + (size_t)colg * 256
                                     : B2b + (size_t)(colg - N1) * 256) + kc;
        *reinterpret_cast<short8*>(&Bs[col * 264 + kc]) =
            *reinterpret_cast<const short8*>(Br);
    }

    __syncthreads();

    // ---- batch 2: A fragments k=128..255, complete under iters 0..3 ----
    short8 A0b[4], A1b[4];
    #pragma unroll
    for (int i = 0; i < 4; ++i) {
        A0b[i] = *reinterpret_cast<const short8*>(Ap0 + 128 + i * 32);
        A1b[i] = *reinterpret_cast<const short8*>(Ap1 + 128 + i * 32);
    }

    f32x4 acc[2][4] = {};
    #pragma unroll
    for (int i = 0; i < 8; ++i) {
        const int k0 = i * 32;
        short8 a0 = (i < 4) ? A0[i] : A0b[i - 4];   // static under unroll
        short8 a1 = (i < 4) ? A1[i] : A1b[i - 4];
        short8 b0 = *reinterpret_cast<const short8*>(&Bs[(0 * 16 + lr) * 264 + kb + k0]);
        short8 b1 = *reinterpret_cast<const short8*>(&Bs[(1 * 16 + lr) * 264 + kb + k0]);
        short8 b2 = *reinterpret_cast<const short8*>(&Bs[(2 * 16 + lr) * 264 + kb + k0]);
        short8 b3 = *reinterpret_cast<const short8*>(&Bs[(3 * 16 + lr) * 264 + kb + k0]);
        acc[0][0] = __builtin_amdgcn_mfma_f32_16x16x32_bf16(a0, b0, acc[0][0], 0, 0, 0);
        acc[0][1] = __builtin_amdgcn_mfma_f32_16x16x32_bf16(a0, b1, acc[0][1], 0, 0, 0);
        acc[0][2] = __builtin_amdgcn_mfma_f32_16x16x32_bf16(a0, b2, acc[0][2], 0, 0, 0);
        acc[0][3] = __builtin_amdgcn_mfma_f32_16x16x32_bf16(a0, b3, acc[0][3], 0, 0, 0);
        acc[1][0] = __builtin_amdgcn_mfma_f32_16x16x32_bf16(a1, b0, acc[1][0], 0, 0, 0);
        acc[1][1] = __builtin_amdgcn_mfma_f32_16x16x32_bf16(a1, b1, acc[1][1], 0, 0, 0);
        acc[1][2] = __builtin_amdgcn_mfma_f32_16x16x32_bf16(a1, b2, acc[1][2], 0, 0, 0);
        acc[1][3] = __builtin_amdgcn_mfma_f32_16x16x32_bf16(a1, b3, acc[1][3], 0, 0, 0);
    }

    // C/D layout: col = l&15, row = (l>>4)*4 + reg  [m89-verified]
    const int orow = (l >> 4) * 4;

    if (jobS) {
        // direct f32 stores (already 64B segments per 16-lane group)
        #pragma unroll
        for (int ct = 0; ct < 4; ++ct) {
            const int col = o0 + ct * 16 + lr;
            if (col >= Ntot) continue;
            const float bsv = (col < N1) ? bias1[col] : bias2[col - N1];
            #pragma unroll
            for (int rt = 0; rt < 2; ++rt) {
                #pragma unroll
                for (int r = 0; r < 4; ++r) {
                    const int row = row0 + rt * 16 + orow + r;
                    if (row < rows)
                        S[(size_t)row * 288 + col] = acc[rt][ct][r] + bsv;
                }
            }
        }
    } else {
        // LDS-staged u16 epilogue (Bs dead after k-loop), head-major output.
        __syncthreads();
        #pragma unroll
        for (int ct = 0; ct < 4; ++ct) {
            const int col = ct * 16 + lr;          // 0..63 within panel
            const float bsv = bias1[o0 + col];     // proj: bias1==bv
            #pragma unroll
            for (int rt = 0; rt < 2; ++rt) {
                #pragma unroll
                for (int r = 0; r < 4; ++r) {
                    const int rowL = w * 32 + rt * 16 + orow + r;   // 0..255
                    Bs[rowL * 64 + col] = f2bf(acc[rt][ct][r] + bsv);
                }
            }
        }
        __syncthreads();
        // coalesced copy-out: 512 threads x 32 u16 (64B contiguous).
        // Head-major: half = one head's 32 channels.
        const int rowL = t >> 1;
        const int head = (o0 >> 5) + (t & 1);      // 0..7
        const int grow = rowTile * 256 + rowL;     // b*P_ + pix
        if (grow < rows) {
            const int bb  = grow / P_;
            const int pix = grow - bb * P_;
            const short8* src = reinterpret_cast<const short8*>(&Bs[rowL * 64 + (t & 1) * 32]);
            short8* dst = reinterpret_cast<short8*>(
                proj + (((size_t)(bb * 8 + head)) * P_ + pix) * 32);
            dst[0] = src[0]; dst[1] = src[1];
            dst[2] = src[2]; dst[3] = src[3];
        }
    }
}

// ---------------------------------------------------------------------------
// Output projection GEMM (R10 hoisted-A, unchanged — f32 out, 64B segments).
// ---------------------------------------------------------------------------
__global__ __launch_bounds__(512) void gemm_out(
    const u16* __restrict__ Av, int rows, int nRowTiles, int npanel,
    const u16* __restrict__ Bb, const float* __restrict__ bias, int Ntot,
    float* __restrict__ Cout)
{
    __shared__ u16 Bs[64 * 264];

    const int bid  = blockIdx.x;
    const int rlo  = bid & 7;
    const int tmp  = bid >> 3;
    const int panel = tmp % npanel;
    const int rowTile = (tmp / npanel) * 8 + rlo;
    if (rowTile >= nRowTiles) return;

    const int t  = threadIdx.x;
    const int w  = t >> 6;
    const int l  = t & 63;
    const int row0 = rowTile * 256 + w * 32;
    const int o0   = panel * 64;
    const int lr = l & 15;
    const int kb = (l >> 4) * 8;

    const int ra0 = min(row0 + lr,      rows - 1);
    const int ra1 = min(row0 + 16 + lr, rows - 1);
    const u16* Ap0 = Av + (size_t)ra0 * 256 + kb;
    const u16* Ap1 = Av + (size_t)ra1 * 256 + kb;

    short8 A0[4], A1[4];
    #pragma unroll
    for (int i = 0; i < 4; ++i) {
        A0[i] = *reinterpret_cast<const short8*>(Ap0 + i * 32);
        A1[i] = *reinterpret_cast<const short8*>(Ap1 + i * 32);
    }

    #pragma unroll
    for (int i = 0; i < 4; ++i) {
        int idx = i * 512 + t;
        int col = idx >> 5;
        int kc  = (idx & 31) * 8;
        int colg = min(o0 + col, Ntot - 1);
        *reinterpret_cast<short8*>(&Bs[col * 264 + kc]) =
            *reinterpret_cast<const short8*>(Bb + (size_t)colg * 256 + kc);
    }

    __syncthreads();

    short8 A0b[4], A1b[4];
    #pragma unroll
    for (int i = 0; i < 4; ++i) {
        A0b[i] = *reinterpret_cast<const short8*>(Ap0 + 128 + i * 32);
        A1b[i] = *reinterpret_cast<const short8*>(Ap1 + 128 + i * 32);
    }

    f32x4 acc[2][4] = {};
    #pragma unroll
    for (int i = 0; i < 8; ++i) {
        const int k0 = i * 32;
        short8 a0 = (i < 4) ? A0[i] : A0b[i - 4];
        short8 a1 = (i < 4) ? A1[i] : A1b[i - 4];
        short8 b0 = *reinterpret_cast<const short8*>(&Bs[(0 * 16 + lr) * 264 + kb + k0]);
        short8 b1 = *reinterpret_cast<const short8*>(&Bs[(1 * 16 + lr) * 264 + kb + k0]);
        short8 b2 = *reinterpret_cast<const short8*>(&Bs[(2 * 16 + lr) * 264 + kb + k0]);
        short8 b3 = *reinterpret_cast<const short8*>(&Bs[(3 * 16 + lr) * 264 + kb + k0]);
        acc[0][0] = __builtin_amdgcn_mfma_f32_16x16x32_bf16(a0, b0, acc[0][0], 0, 0, 0);
        acc[0][1] = __builtin_amdgcn_mfma_f32_16x16x32_bf16(a0, b1, acc[0][1], 0, 0, 0);
        acc[0][2] = __builtin_amdgcn_mfma_f32_16x16x32_bf16(a0, b2, acc[0][2], 0, 0, 0);
        acc[0][3] = __builtin_amdgcn_mfma_f32_16x16x32_bf16(a0, b3, acc[0][3], 0, 0, 0);
        acc[1][0] = __builtin_amdgcn_mfma_f32_16x16x32_bf16(a1, b0, acc[1][0], 0, 0, 0);
        acc[1][1] = __builtin_amdgcn_mfma_f32_16x16x32_bf16(a1, b1, acc[1][1], 0, 0, 0);
        acc[1][2] = __builtin_amdgcn_mfma_f32_16x16x32_bf16(a1, b2, acc[1][2], 0, 0, 0);
        acc[1][3] = __builtin_amdgcn_mfma_f32_16x16x32_bf16(a1, b3, acc[1][3], 0, 0, 0);
    }

    const int orow = (l >> 4) * 4;
    #pragma unroll
    for (int ct = 0; ct < 4; ++ct) {
        const int col = o0 + ct * 16 + lr;
        if (col >= Ntot) continue;
        const float bsv = bias[col];
        #pragma unroll
        for (int rt = 0; rt < 2; ++rt) {
            #pragma unroll
            for (int r = 0; r < 4; ++r) {
                const int row = row0 + rt * 16 + orow + r;
                if (row < rows)
                    Cout[(size_t)row * Ntot + col] = acc[rt][ct][r] + bsv;
            }
        }
    }
}

// ---------------------------------------------------------------------------
// Sampling (R1 structure, 6x confirmed; HEAD-MAJOR proj addressing).
// midx stores pix*32 (u16 units within a head's plane); per-thread projb
// selects (b, head). x-adjacent corners now 64B apart -> line sharing.
// ---------------------------------------------------------------------------
__global__ __launch_bounds__(256) void sample_kernel(
    const float* __restrict__ S,       // [B*NQ, 288]
    const float* __restrict__ refp,    // [B*NQ, 2]
    const u16* __restrict__ proj,      // [b][m][pix][32] bf16
    u16* __restrict__ out2)            // [B*NQ, 256] bf16
{
    constexpr int Wd[3]   = {100, 50, 25};
    constexpr int offs[3] = {0, 10000, 12500};

    __shared__ int   midx[192][4];
    __shared__ float mw[192][4];

    const int t = threadIdx.x;

    if (t < 192) {
        const int q  = t / 96;
        const int tq = t % 96;
        const int tm = tq / 12;      // head
        const int tj = tq % 12;      // point = l*4+k
        const int bq = blockIdx.x * 2 + q;
        const float* Sq = S + (size_t)bq * 288;

        float lg[12], mx = -1e30f;
        #pragma unroll
        for (int jj = 0; jj < 12; ++jj) {
            lg[jj] = Sq[192 + tm * 12 + jj];
            mx = fmaxf(mx, lg[jj]);
        }
        float sum = 0.f;
        #pragma unroll
        for (int jj = 0; jj < 12; ++jj) sum += __expf(lg[jj] - mx);
        const float attn = __expf(lg[tj] - mx) / sum;

        const int l  = tj >> 2;
        const int Wl = Wd[l];
        const float refx = refp[(size_t)bq * 2 + 0];
        const float refy = refp[(size_t)bq * 2 + 1];
        const float ox = Sq[(tm * 12 + tj) * 2 + 0];
        const float oy = Sq[(tm * 12 + tj) * 2 + 1];
        const float px = refx * (float)Wl + ox - 0.5f;   // H==W per level
        const float py = refy * (float)Wl + oy - 0.5f;
        const float x0f = floorf(px), y0f = floorf(py);
        const float wx1 = px - x0f, wy1 = py - y0f;
        const float wx0 = 1.f - wx1, wy0 = 1.f - wy1;
        const int x0 = (int)x0f, y0 = (int)y0f;
        const int x1 = x0 + 1, y1 = y0 + 1;
        const bool vx0 = (unsigned)x0 < (unsigned)Wl;
        const bool vx1 = (unsigned)x1 < (unsigned)Wl;
        const bool vy0 = (unsigned)y0 < (unsigned)Wl;
        const bool vy1 = (unsigned)y1 < (unsigned)Wl;
        const int base = offs[l];
        midx[t][0] = (vx0 && vy0) ? ((base + y0 * Wl + x0) * 32) : 0;
        midx[t][1] = (vx1 && vy0) ? ((base + y0 * Wl + x1) * 32) : 0;
        midx[t][2] = (vx0 && vy1) ? ((base + y1 * Wl + x0) * 32) : 0;
        midx[t][3] = (vx1 && vy1) ? ((base + y1 * Wl + x1) * 32) : 0;
        mw[t][0] = (vx0 && vy0) ? attn * wx0 * wy0 : 0.f;
        mw[t][1] = (vx1 && vy0) ? attn * wx1 * wy0 : 0.f;
        mw[t][2] = (vx0 && vy1) ? attn * wx0 * wy1 : 0.f;
        mw[t][3] = (vx1 && vy1) ? attn * wx1 * wy1 : 0.f;
    }
    __syncthreads();

    const int qi  = t >> 7;
    const int tt  = t & 127;
    const int mh  = tt >> 4;
    const int d16 = tt & 15;
    const int bq2 = blockIdx.x * 2 + qi;
    const int b   = bq2 / NQ_;
    const u16* projb = proj + ((size_t)(b * 8 + mh) * P_) * 32 + 2 * d16;

    float acc0 = 0.f, acc1 = 0.f;

    #pragma unroll
    for (int j = 0; j < 12; ++j) {
        const int mj = qi * 96 + mh * 12 + j;
        const int4   o  = *reinterpret_cast<const int4*>(midx[mj]);
        const float4 ww = *reinterpret_cast<const float4*>(mw[mj]);
        const unsigned u00 = *reinterpret_cast<const unsigned*>(projb + o.x);
        const unsigned u10 = *reinterpret_cast<const unsigned*>(projb + o.y);
        const unsigned u01 = *reinterpret_cast<const unsigned*>(projb + o.z);
        const unsigned u11 = *reinterpret_cast<const unsigned*>(projb + o.w);
        union { unsigned u; float f; } c0, c1;
        c0.u = u00 << 16;          c1.u = u00 & 0xffff0000u;
        acc0 = fmaf(ww.x, c0.f, acc0); acc1 = fmaf(ww.x, c1.f, acc1);
        c0.u = u10 << 16;          c1.u = u10 & 0xffff0000u;
        acc0 = fmaf(ww.y, c0.f, acc0); acc1 = fmaf(ww.y, c1.f, acc1);
        c0.u = u01 << 16;          c1.u = u01 & 0xffff0000u;
        acc0 = fmaf(ww.z, c0.f, acc0); acc1 = fmaf(ww.z, c1.f, acc1);
        c0.u = u11 << 16;          c1.u = u11 & 0xffff0000u;
        acc0 = fmaf(ww.w, c0.f, acc0); acc1 = fmaf(ww.w, c1.f, acc1);
    }

    const unsigned packed = (unsigned)f2bf(acc0) | ((unsigned)f2bf(acc1) << 16);
    *reinterpret_cast<unsigned*>(out2 + (size_t)bq2 * 256 + mh * 32 + 2 * d16) = packed;
}

// ---------------------------------------------------------------------------
extern "C" void kernel_launch(void* const* d_in, const int* in_sizes, int n_in,
                              void* d_out, int out_size, void* d_ws, size_t ws_size,
                              hipStream_t stream)
{
    const float* query = (const float*)d_in[0];
    const float* refp  = (const float*)d_in[1];
    const float* v0    = (const float*)d_in[2];
    const float* v1    = (const float*)d_in[3];
    const float* v2    = (const float*)d_in[4];
    const float* Wv    = (const float*)d_in[5];
    const float* bv    = (const float*)d_in[6];
    const float* Ws    = (const float*)d_in[7];
    const float* bs    = (const float*)d_in[8];
    const float* Wa    = (const float*)d_in[9];
    const float* ba    = (const float*)d_in[10];
    const float* Wo    = (const float*)d_in[11];
    const float* bo    = (const float*)d_in[12];
    float* out = (float*)d_out;

    char* wsb = (char*)d_ws;
    u16*   proj  = (u16*)wsb;    wsb += (size_t)B_ * P_ * 256 * 2;   // 13.44 MB
    float* S     = (float*)wsb;  wsb += (size_t)B_ * NQ_ * 288 * 4;  // 23.04 MB
    u16*   Vt    = (u16*)wsb;    wsb += (size_t)B_ * P_ * 256 * 2;   // 13.44 MB
    u16*   out2  = (u16*)wsb;    wsb += (size_t)B_ * NQ_ * 256 * 2;  // 10.24 MB
    u16*   qbf   = (u16*)wsb;    wsb += (size_t)B_ * NQ_ * 256 * 2;  // 10.24 MB
    u16*   wb    = (u16*)wsb;    wsb += (size_t)204800 * 2;          // 0.4 MB
    u16* Wvb = wb;
    u16* Wsb = wb + 65536;
    u16* Wab = wb + 114688;
    u16* Wob = wb + 139264;

    // 0) merged prep: transpose (3768) + weight cvt (100) + query cvt (2500)
    prep<<<dim3(6368), dim3(256), 0, stream>>>(
        v0, v1, v2, Vt, Wv, Ws, Wa, Wo, wb, query, qbf);

    // 1+2) FUSED 8-wave hoisted-A + head-major proj epilogue: 416+400 blocks
    gemm_fused<<<dim3(816), dim3(512), 0, stream>>>(
        Vt, qbf, Wvb, bv, Wsb, bs, Wab, ba, proj, S);

    // 3) softmax + bilinear sampling -> out2 bf16 (2 queries / block)
    sample_kernel<<<dim3(NQ_), dim3(256), 0, stream>>>(S, refp, proj, out2);

    // 4) output projection -> d_out f32. 320 blocks.
    gemm_out<<<dim3(320), dim3(512), 0, stream>>>(
        out2, B_ * NQ_, 79, 4, Wob, bo, 256, out);
}